// Round 1
// baseline (4206.067 us; speedup 1.0000x reference)
//
#include <hip/hip_runtime.h>
#include <hip/hip_bf16.h>
#include <math.h>

// Problem constants (match reference)
#define B_   64
#define P_   150   // n_pred
#define T_   150   // n_true
#define C_   81
#define M_   151   // columns incl dummy col 0
#define NOOBJ 80

// ---------------------------------------------------------------------------
// Kernel 1: cost matrix [B, P, T] in f32
// ---------------------------------------------------------------------------
__global__ void cost_kernel(const float* __restrict__ prob,
                            const float* __restrict__ pbox,
                            const float* __restrict__ labels,
                            float* __restrict__ cost) {
    int idx = blockIdx.x * blockDim.x + threadIdx.x;
    const int total = B_ * P_ * T_;
    if (idx >= total) return;
    int t  = idx % T_;
    int p  = (idx / T_) % P_;
    int b  = idx / (P_ * T_);

    const float* lb5 = labels + ((size_t)b * T_ + t) * 5;
    const float inv = 1.0f / 320.0f;
    float lcx = lb5[0] * inv, lcy = lb5[1] * inv, lw = lb5[2] * inv, lh = lb5[3] * inv;
    int cls = (int)lb5[4];

    const float* pb = pbox + ((size_t)b * P_ + p) * 4;
    float pcx = pb[0], pcy = pb[1], pw = pb[2], ph = pb[3];

    float nll = -logf(prob[((size_t)b * P_ + p) * C_ + cls]);

    float l1 = 0.25f * (fabsf(pcx - lcx) + fabsf(pcy - lcy) +
                        fabsf(pw - lw)   + fabsf(ph - lh));

    float px0 = pcx - 0.5f * pw, py0 = pcy - 0.5f * ph;
    float px1 = pcx + 0.5f * pw, py1 = pcy + 0.5f * ph;
    float lx0 = lcx - 0.5f * lw, ly0 = lcy - 0.5f * lh;
    float lx1 = lcx + 0.5f * lw, ly1 = lcy + 0.5f * lh;

    float ltx = fmaxf(px0, lx0), lty = fmaxf(py0, ly0);
    float rbx = fminf(px1, lx1), rby = fminf(py1, ly1);
    float iw = fmaxf(rbx - ltx, 0.f), ih = fmaxf(rby - lty, 0.f);
    float inter = iw * ih;
    float ap = (px1 - px0) * (py1 - py0);
    float al = (lx1 - lx0) * (ly1 - ly0);
    float un = ap + al - inter;
    float iou = inter / (un + 1e-7f);

    float cx0 = fminf(px0, lx0), cy0 = fminf(py0, ly0);
    float cx1 = fmaxf(px1, lx1), cy1 = fmaxf(py1, ly1);
    float cw = fmaxf(cx1 - cx0, 0.f), ch = fmaxf(cy1 - cy0, 0.f);
    float enc = cw * ch;
    float giou = iou - (enc - un) / (enc + 1e-7f);
    float gl = 1.0f - giou;

    float mask = (cls != NOOBJ) ? 1.0f : 0.0f;
    cost[idx] = nll + (5.0f * l1 + 2.0f * gl) * mask;
}

// ---------------------------------------------------------------------------
// Kernel 2: Hungarian (JV shortest augmenting path), one wave per batch.
// Exact same algorithm as the numpy reference, f64 duals, first-index
// argmin tie-break. State + cost tile live in LDS.
// ---------------------------------------------------------------------------
#define SM_COST   (P_ * T_ * 4)          // 90000 B (8-aligned)
#define SM_U      (SM_COST)
#define SM_V      (SM_U    + M_ * 8)
#define SM_MINV   (SM_V    + M_ * 8)
#define SM_P      (SM_MINV + M_ * 8)
#define SM_WAY    (SM_P    + M_ * 4)
#define SM_USED   (SM_WAY  + M_ * 4)
#define SM_TOTAL  (SM_USED + M_ * 4)     // 95436 -> launch with 95440

__global__ __launch_bounds__(64) void hungarian_kernel(const float* __restrict__ cost,
                                                       int* __restrict__ assign) {
    const int b = blockIdx.x;
    const int lane = threadIdx.x;
    const float* Cg = cost + (size_t)b * (P_ * T_);

    extern __shared__ char smem[];
    float*  cl   = (float*) smem;
    double* u    = (double*)(smem + SM_U);
    double* v    = (double*)(smem + SM_V);
    double* minv = (double*)(smem + SM_MINV);
    int*    p    = (int*)   (smem + SM_P);
    int*    way  = (int*)   (smem + SM_WAY);
    int*    used = (int*)   (smem + SM_USED);

    // stage cost tile into LDS (float2: 11250 pairs)
    for (int i = lane; i < (P_ * T_) / 2; i += 64)
        ((float2*)cl)[i] = ((const float2*)Cg)[i];

    for (int j = lane; j < M_; j += 64) {
        u[j] = 0.0; v[j] = 0.0; p[j] = 0; way[j] = 0;
    }
    __syncthreads();

    const double INF = __builtin_inf();

    for (int i = 1; i <= P_; ++i) {
        for (int j = lane; j < M_; j += 64) { minv[j] = INF; used[j] = 0; }
        if (lane == 0) p[0] = i;
        __syncthreads();

        int j0 = 0;
        while (true) {
            if (lane == 0) used[j0] = 1;
            __syncthreads();                       // (1) used + prev updates visible

            int    i0  = p[j0];                    // uniform broadcast read
            double ui0 = u[i0];

            // scan free columns, update minv/way, local argmin
            double bestv = INF;
            int    bestj = M_;                     // sentinel > any real col
            #pragma unroll
            for (int s = 0; s < 3; ++s) {
                int j = 1 + lane + s * 64;         // 1..150 (guarded)
                if (j <= T_ && !used[j]) {
                    double cur = (double)cl[(i0 - 1) * T_ + (j - 1)] - ui0 - v[j];
                    if (cur < minv[j]) { minv[j] = cur; way[j] = j0; }
                    double mv = minv[j];
                    if (mv < bestv) { bestv = mv; bestj = j; }
                }
            }
            // wave argmin, tie-break toward smaller j (== np.argmin first index)
            #pragma unroll
            for (int off = 32; off >= 1; off >>= 1) {
                double ov = __shfl_xor(bestv, off);
                int    oj = __shfl_xor(bestj, off);
                if (ov < bestv || (ov == bestv && oj < bestj)) { bestv = ov; bestj = oj; }
            }
            double delta = bestv;
            int    j1    = bestj;
            __syncthreads();                       // (2) scan reads done before updates

            #pragma unroll
            for (int s = 0; s < 3; ++s) {
                int j = lane + s * 64;             // 0..150 (guarded)
                if (j < M_) {
                    if (used[j]) { u[p[j]] += delta; v[j] -= delta; }
                    else         { minv[j] -= delta; }
                }
            }
            __syncthreads();                       // (3) updates visible

            j0 = j1;
            if (p[j0] == 0) break;                 // uniform read
        }

        // augment path (serial, lane 0)
        if (lane == 0) {
            int jj = j0;
            while (jj != 0) { int jn = way[jj]; p[jj] = p[jn]; jj = jn; }
        }
        __syncthreads();
    }

    // extract: row p[j]-1 is matched to column j-1
    for (int j = 1 + lane; j <= T_; j += 64) {
        int row = p[j] - 1;
        assign[b * P_ + row] = j - 1;
    }
}

// ---------------------------------------------------------------------------
// Kernel 3: per-i partial loss: mean over (b,k) of cost[b, k, assign_i[k]]
// ---------------------------------------------------------------------------
__global__ void gather_kernel(const float* __restrict__ cost,
                              const int* __restrict__ assign,
                              double* __restrict__ partial) {
    const int i = blockIdx.x;
    const int* a = assign + i * P_;
    double s = 0.0;
    for (int idx = threadIdx.x; idx < B_ * P_; idx += blockDim.x) {
        int b = idx / P_;
        int k = idx % P_;
        s += (double)cost[((size_t)b * P_ + k) * T_ + a[k]];
    }
    __shared__ double red[256];
    red[threadIdx.x] = s;
    __syncthreads();
    for (int off = 128; off >= 1; off >>= 1) {
        if (threadIdx.x < off) red[threadIdx.x] += red[threadIdx.x + off];
        __syncthreads();
    }
    if (threadIdx.x == 0) partial[i] = red[0] / (double)(B_ * P_);
}

// ---------------------------------------------------------------------------
// Kernel 4: final sum (deterministic order) -> f32 scalar
// ---------------------------------------------------------------------------
__global__ void finalize_kernel(const double* __restrict__ partial,
                                float* __restrict__ out) {
    if (threadIdx.x == 0 && blockIdx.x == 0) {
        double s = 0.0;
        for (int i = 0; i < B_; ++i) s += partial[i];
        out[0] = (float)s;
    }
}

// ---------------------------------------------------------------------------
extern "C" void kernel_launch(void* const* d_in, const int* in_sizes, int n_in,
                              void* d_out, int out_size, void* d_ws, size_t ws_size,
                              hipStream_t stream) {
    const float* prob   = (const float*)d_in[0];   // [64,150,81]
    const float* pbox   = (const float*)d_in[1];   // [64,150,4]
    const float* labels = (const float*)d_in[2];   // [64,150,5]
    float* out = (float*)d_out;

    // workspace layout
    char* ws = (char*)d_ws;
    float*  cost    = (float*) ws;                               // 5,760,000 B
    int*    assign  = (int*)   (ws + (size_t)B_ * P_ * T_ * 4);  // 38,400 B
    double* partial = (double*)(ws + (size_t)B_ * P_ * T_ * 4 + (size_t)B_ * P_ * 4);

    const int total = B_ * P_ * T_;
    cost_kernel<<<(total + 255) / 256, 256, 0, stream>>>(prob, pbox, labels, cost);

    hungarian_kernel<<<B_, 64, 95440, stream>>>(cost, assign);

    gather_kernel<<<B_, 256, 0, stream>>>(cost, assign, partial);

    finalize_kernel<<<1, 64, 0, stream>>>(partial, out);
}

// Round 2
// 2921.914 us; speedup vs baseline: 1.4395x; 1.4395x over previous
//
#include <hip/hip_runtime.h>
#include <hip/hip_bf16.h>
#include <math.h>

// Problem constants (match reference)
#define B_   64
#define P_   150   // n_pred (rows)
#define T_   150   // n_true (cols)
#define C_   81
#define NOOBJ 80

// ---------------------------------------------------------------------------
// Kernel 1: cost matrix [B, P, T] in f32
// ---------------------------------------------------------------------------
__global__ void cost_kernel(const float* __restrict__ prob,
                            const float* __restrict__ pbox,
                            const float* __restrict__ labels,
                            float* __restrict__ cost) {
    int idx = blockIdx.x * blockDim.x + threadIdx.x;
    const int total = B_ * P_ * T_;
    if (idx >= total) return;
    int t  = idx % T_;
    int p  = (idx / T_) % P_;
    int b  = idx / (P_ * T_);

    const float* lb5 = labels + ((size_t)b * T_ + t) * 5;
    const float inv = 1.0f / 320.0f;
    float lcx = lb5[0] * inv, lcy = lb5[1] * inv, lw = lb5[2] * inv, lh = lb5[3] * inv;
    int cls = (int)lb5[4];

    const float* pb = pbox + ((size_t)b * P_ + p) * 4;
    float pcx = pb[0], pcy = pb[1], pw = pb[2], ph = pb[3];

    float nll = -logf(prob[((size_t)b * P_ + p) * C_ + cls]);

    float l1 = 0.25f * (fabsf(pcx - lcx) + fabsf(pcy - lcy) +
                        fabsf(pw - lw)   + fabsf(ph - lh));

    float px0 = pcx - 0.5f * pw, py0 = pcy - 0.5f * ph;
    float px1 = pcx + 0.5f * pw, py1 = pcy + 0.5f * ph;
    float lx0 = lcx - 0.5f * lw, ly0 = lcy - 0.5f * lh;
    float lx1 = lcx + 0.5f * lw, ly1 = lcy + 0.5f * lh;

    float ltx = fmaxf(px0, lx0), lty = fmaxf(py0, ly0);
    float rbx = fminf(px1, lx1), rby = fminf(py1, ly1);
    float iw = fmaxf(rbx - ltx, 0.f), ih = fmaxf(rby - lty, 0.f);
    float inter = iw * ih;
    float ap = (px1 - px0) * (py1 - py0);
    float al = (lx1 - lx0) * (ly1 - ly0);
    float un = ap + al - inter;
    float iou = inter / (un + 1e-7f);

    float cx0 = fminf(px0, lx0), cy0 = fminf(py0, ly0);
    float cx1 = fmaxf(px1, lx1), cy1 = fmaxf(py1, ly1);
    float cw = fmaxf(cx1 - cx0, 0.f), ch = fmaxf(cy1 - cy0, 0.f);
    float enc = cw * ch;
    float giou = iou - (enc - un) / (enc + 1e-7f);
    float gl = 1.0f - giou;

    float mask = (cls != NOOBJ) ? 1.0f : 0.0f;
    cost[idx] = nll + (5.0f * l1 + 2.0f * gl) * mask;
}

// ---------------------------------------------------------------------------
// Kernel 2: Hungarian (JV), one wave per batch. Register-resident state:
// each lane owns columns j = 1+lane, 65+lane, 129+lane. v/minv/way/p in
// registers; only cost tile + u[] (row duals) in LDS. Zero barriers in the
// main loop (single-wave lockstep; DS ops in-order per wave; the u-scatter
// set [rows of used cols] is disjoint from the prefetched u[i0] [row of the
// just-found free col]).
// ---------------------------------------------------------------------------
#define SM_U      (P_ * T_ * 4)           // after 90000 B cost tile
#define SM_TOTAL  (SM_U + 152 * 8)        // u[151], pad to 8B

__device__ __forceinline__ int sel3i(int s, int a, int b, int c) {
    return s == 0 ? a : (s == 1 ? b : c);
}

__global__ __launch_bounds__(64) void hungarian_kernel(const float* __restrict__ cost,
                                                       int* __restrict__ assign) {
    const int b = blockIdx.x;
    const int lane = threadIdx.x;
    const float* Cg = cost + (size_t)b * (P_ * T_);

    extern __shared__ char smem[];
    float*  cl = (float*)smem;             // [150*150] f32
    double* u  = (double*)(smem + SM_U);   // [151] f64 row duals

    // stage cost tile (float4: 5625 vec4 loads)
    for (int i4 = lane; i4 < (P_ * T_) / 4; i4 += 64)
        ((float4*)cl)[i4] = ((const float4*)Cg)[i4];
    for (int r = lane; r <= P_; r += 64) u[r] = 0.0;
    __syncthreads();   // once; init visibility

    // per-lane column slots
    const int ja = 1 + lane;          // s=0, cols 1..64
    const int jb = 65 + lane;         // s=1, cols 65..128
    const int jc = 129 + lane;        // s=2, cols 129..192 (valid <=150)
    const bool va2 = (jc <= T_);      // lanes 0..21
    double v0 = 0.0, v1 = 0.0, v2 = 0.0;   // column duals
    int pa = 0, pb = 0, pc = 0;            // p[j]: row assigned to col (0=none)

    const double INF = __builtin_inf();

    for (int i = 1; i <= P_; ++i) {
        double mv0 = INF, mv1 = INF, mv2 = INF;
        int w0 = 0, w1 = 0, w2 = 0;   // way[j]
        int um = 0;                   // used bitmask per slot
        int j0 = 0;

        // prefetch for iteration 0: i0 = i
        double ui0 = u[i];
        int base = (i - 1) * T_ - 1;
        float c0 = cl[base + ja];
        float c1 = cl[base + jb];
        float c2 = cl[base + (va2 ? jc : T_)];

        while (true) {
            // mark used[j0] (col 0 handled implicitly via lane0 u[i] update)
            if (j0 > 0 && lane == ((j0 - 1) & 63)) um |= (1 << ((j0 - 1) >> 6));

            // scan free columns + local argmin (slot order => smaller j first)
            double bestv = INF; int bestj = 1 << 20;
            if (!(um & 1)) {
                double cur = ((double)c0 - ui0) - v0;
                if (cur < mv0) { mv0 = cur; w0 = j0; }
                if (mv0 < bestv) { bestv = mv0; bestj = ja; }
            }
            if (!(um & 2)) {
                double cur = ((double)c1 - ui0) - v1;
                if (cur < mv1) { mv1 = cur; w1 = j0; }
                if (mv1 < bestv) { bestv = mv1; bestj = jb; }
            }
            if (va2 && !(um & 4)) {
                double cur = ((double)c2 - ui0) - v2;
                if (cur < mv2) { mv2 = cur; w2 = j0; }
                if (mv2 < bestv) { bestv = mv2; bestj = jc; }
            }

            // wave argmin, first-index tie-break (== np.argmin)
            #pragma unroll
            for (int off = 32; off >= 1; off >>= 1) {
                double ov = __shfl_xor(bestv, off);
                int    oj = __shfl_xor(bestj, off);
                if (ov < bestv || (ov == bestv && oj < bestj)) { bestv = ov; bestj = oj; }
            }
            const double delta = bestv;
            const int j1 = bestj;

            // dual/minv updates (register-only except u scatter, off critical path)
            if (um & 1) { v0 -= delta; double t = u[pa]; u[pa] = t + delta; }
            else        { mv0 -= delta; }
            if (um & 2) { v1 -= delta; double t = u[pb]; u[pb] = t + delta; }
            else        { mv1 -= delta; }
            if (va2) {
                if (um & 4) { v2 -= delta; double t = u[pc]; u[pc] = t + delta; }
                else        { mv2 -= delta; }
            }
            if (lane == 0) { double t = u[i]; u[i] = t + delta; }   // col 0: p[0]=i

            // p[j1] via shuffle; prefetch next iteration's u/cost row
            int s1 = (j1 - 1) >> 6, l1 = (j1 - 1) & 63;
            int pj = __shfl(sel3i(s1, pa, pb, pc), l1);
            j0 = j1;
            if (pj == 0) break;
            ui0 = u[pj];
            base = (pj - 1) * T_ - 1;
            c0 = cl[base + ja];
            c1 = cl[base + jb];
            c2 = cl[base + (va2 ? jc : T_)];
        }

        // augment: walk way chain wave-uniformly via shuffles
        int jj = j0;
        while (jj != 0) {
            int sj = (jj - 1) >> 6, lj = (jj - 1) & 63;
            int jn = __shfl(sel3i(sj, w0, w1, w2), lj);
            int rown;
            if (jn == 0) rown = i;
            else {
                int sn = (jn - 1) >> 6, ln = (jn - 1) & 63;
                rown = __shfl(sel3i(sn, pa, pb, pc), ln);
            }
            if (lane == lj) {
                if (sj == 0) pa = rown; else if (sj == 1) pb = rown; else pc = rown;
            }
            jj = jn;
        }
    }

    // extract: col j assigned row pa-1; perfect matching covers all rows
    assign[b * P_ + (pa - 1)] = ja - 1;
    assign[b * P_ + (pb - 1)] = jb - 1;
    if (va2) assign[b * P_ + (pc - 1)] = jc - 1;
}

// ---------------------------------------------------------------------------
// Kernel 3: per-i partial loss: mean over (b,k) of cost[b, k, assign_i[k]]
// ---------------------------------------------------------------------------
__global__ void gather_kernel(const float* __restrict__ cost,
                              const int* __restrict__ assign,
                              double* __restrict__ partial) {
    const int i = blockIdx.x;
    const int* a = assign + i * P_;
    double s = 0.0;
    for (int idx = threadIdx.x; idx < B_ * P_; idx += blockDim.x) {
        int b = idx / P_;
        int k = idx % P_;
        s += (double)cost[((size_t)b * P_ + k) * T_ + a[k]];
    }
    __shared__ double red[256];
    red[threadIdx.x] = s;
    __syncthreads();
    for (int off = 128; off >= 1; off >>= 1) {
        if (threadIdx.x < off) red[threadIdx.x] += red[threadIdx.x + off];
        __syncthreads();
    }
    if (threadIdx.x == 0) partial[i] = red[0] / (double)(B_ * P_);
}

// ---------------------------------------------------------------------------
// Kernel 4: final sum (deterministic order) -> f32 scalar
// ---------------------------------------------------------------------------
__global__ void finalize_kernel(const double* __restrict__ partial,
                                float* __restrict__ out) {
    if (threadIdx.x == 0 && blockIdx.x == 0) {
        double s = 0.0;
        for (int i = 0; i < B_; ++i) s += partial[i];
        out[0] = (float)s;
    }
}

// ---------------------------------------------------------------------------
extern "C" void kernel_launch(void* const* d_in, const int* in_sizes, int n_in,
                              void* d_out, int out_size, void* d_ws, size_t ws_size,
                              hipStream_t stream) {
    const float* prob   = (const float*)d_in[0];   // [64,150,81]
    const float* pbox   = (const float*)d_in[1];   // [64,150,4]
    const float* labels = (const float*)d_in[2];   // [64,150,5]
    float* out = (float*)d_out;

    char* ws = (char*)d_ws;
    float*  cost    = (float*) ws;                               // 5,760,000 B
    int*    assign  = (int*)   (ws + (size_t)B_ * P_ * T_ * 4);  // 38,400 B
    double* partial = (double*)(ws + (size_t)B_ * P_ * T_ * 4 + (size_t)B_ * P_ * 4);

    const int total = B_ * P_ * T_;
    cost_kernel<<<(total + 255) / 256, 256, 0, stream>>>(prob, pbox, labels, cost);

    hungarian_kernel<<<B_, 64, SM_TOTAL, stream>>>(cost, assign);

    gather_kernel<<<B_, 256, 0, stream>>>(cost, assign, partial);

    finalize_kernel<<<1, 64, 0, stream>>>(partial, out);
}

// Round 3
// 2156.436 us; speedup vs baseline: 1.9505x; 1.3550x over previous
//
#include <hip/hip_runtime.h>
#include <hip/hip_bf16.h>
#include <math.h>

// Problem constants (match reference)
#define B_   64
#define P_   150   // n_pred (rows)
#define T_   150   // n_true (cols)
#define C_   81
#define NOOBJ 80

// ---------------------------------------------------------------------------
// Kernel 1: cost matrix [B, P, T] in f32
// ---------------------------------------------------------------------------
__global__ void cost_kernel(const float* __restrict__ prob,
                            const float* __restrict__ pbox,
                            const float* __restrict__ labels,
                            float* __restrict__ cost) {
    int idx = blockIdx.x * blockDim.x + threadIdx.x;
    const int total = B_ * P_ * T_;
    if (idx >= total) return;
    int t  = idx % T_;
    int p  = (idx / T_) % P_;
    int b  = idx / (P_ * T_);

    const float* lb5 = labels + ((size_t)b * T_ + t) * 5;
    const float inv = 1.0f / 320.0f;
    float lcx = lb5[0] * inv, lcy = lb5[1] * inv, lw = lb5[2] * inv, lh = lb5[3] * inv;
    int cls = (int)lb5[4];

    const float* pb = pbox + ((size_t)b * P_ + p) * 4;
    float pcx = pb[0], pcy = pb[1], pw = pb[2], ph = pb[3];

    float nll = -logf(prob[((size_t)b * P_ + p) * C_ + cls]);

    float l1 = 0.25f * (fabsf(pcx - lcx) + fabsf(pcy - lcy) +
                        fabsf(pw - lw)   + fabsf(ph - lh));

    float px0 = pcx - 0.5f * pw, py0 = pcy - 0.5f * ph;
    float px1 = pcx + 0.5f * pw, py1 = pcy + 0.5f * ph;
    float lx0 = lcx - 0.5f * lw, ly0 = lcy - 0.5f * lh;
    float lx1 = lcx + 0.5f * lw, ly1 = lcy + 0.5f * lh;

    float ltx = fmaxf(px0, lx0), lty = fmaxf(py0, ly0);
    float rbx = fminf(px1, lx1), rby = fminf(py1, ly1);
    float iw = fmaxf(rbx - ltx, 0.f), ih = fmaxf(rby - lty, 0.f);
    float inter = iw * ih;
    float ap = (px1 - px0) * (py1 - py0);
    float al = (lx1 - lx0) * (ly1 - ly0);
    float un = ap + al - inter;
    float iou = inter / (un + 1e-7f);

    float cx0 = fminf(px0, lx0), cy0 = fminf(py0, ly0);
    float cx1 = fmaxf(px1, lx1), cy1 = fmaxf(py1, ly1);
    float cw = fmaxf(cx1 - cx0, 0.f), ch = fmaxf(cy1 - cy0, 0.f);
    float enc = cw * ch;
    float giou = iou - (enc - un) / (enc + 1e-7f);
    float gl = 1.0f - giou;

    float mask = (cls != NOOBJ) ? 1.0f : 0.0f;
    cost[idx] = nll + (5.0f * l1 + 2.0f * gl) * mask;
}

// ---------------------------------------------------------------------------
// Kernel 2: Hungarian (JV), one wave per batch, register-resident state.
// Argmin via DPP min-reduce on an orderable f32 key + exact f64 tie resolve
// (bit-identical to numpy: (c-u)-v order, first-index tie-break).
// ---------------------------------------------------------------------------
#define SM_U      (P_ * T_ * 4)           // after 90000 B cost tile (8B aligned)
#define SM_TOTAL  (SM_U + 152 * 8)

__device__ __forceinline__ unsigned ord32(float f) {
    unsigned bits = __float_as_uint(f);
    return (bits & 0x80000000u) ? ~bits : (bits | 0x80000000u);
}

// one DPP min step: ctrl must be a literal
#define DPPMIN(x, ctrl)                                                          \
    do {                                                                         \
        unsigned _t = (unsigned)__builtin_amdgcn_update_dpp(                     \
            (int)(x), (int)(x), (ctrl), 0xF, 0xF, false);                        \
        (x) = (_t < (x)) ? _t : (x);                                             \
    } while (0)

__device__ __forceinline__ int sel3i(int s, int a, int b, int c) {
    return s == 0 ? a : (s == 1 ? b : c);
}

__global__ __launch_bounds__(64) void hungarian_kernel(const float* __restrict__ cost,
                                                       int* __restrict__ assign) {
    const int b = blockIdx.x;
    const int lane = threadIdx.x;
    const float* Cg = cost + (size_t)b * (P_ * T_);

    extern __shared__ char smem[];
    float*  cl = (float*)smem;             // [150*150] f32 cost tile
    double* u  = (double*)(smem + SM_U);   // [151] f64 row duals

    for (int i4 = lane; i4 < (P_ * T_) / 4; i4 += 64)
        ((float4*)cl)[i4] = ((const float4*)Cg)[i4];
    for (int r = lane; r <= P_; r += 64) u[r] = 0.0;
    __syncthreads();

    // per-lane column slots
    const int ja = 1 + lane;            // slot 0: cols 1..64
    const int jb = 65 + lane;           // slot 1: cols 65..128
    const int jc = 129 + lane;          // slot 2: cols 129..192 (valid <=150)
    const bool va2 = (jc <= T_);        // lanes 0..21
    const int jcs = va2 ? jc : T_;      // safe address for slot-2 loads
    double v0 = 0.0, v1 = 0.0, v2 = 0.0;    // column duals
    int pa = 0, pb = 0, pc = 0;             // p[j]: row matched to col (0=none)

    const double INF = __builtin_inf();

    for (int i = 1; i <= P_; ++i) {
        double mv0 = INF, mv1 = INF, mv2 = INF;
        int w0 = 0, w1 = 0, w2 = 0;
        int um = va2 ? 0 : 4;           // invalid slot2 marked used
        int j0 = 0;

        // prefetch iteration 0: i0 = i
        double ui0 = u[i];
        int base = (i - 1) * T_ - 1;
        float c0 = cl[base + ja];
        float c1 = cl[base + jb];
        float c2 = cl[base + jcs];

        while (true) {
            // mark used[j0]
            if (j0 > 0 && lane == ((j0 - 1) & 63)) um |= (1 << ((j0 - 1) >> 6));

            // scan free columns (numpy order: (c - u) - v), update minv/way
            double cur0 = ((double)c0 - ui0) - v0;
            double cur1 = ((double)c1 - ui0) - v1;
            double cur2 = ((double)c2 - ui0) - v2;
            if (!(um & 1) && cur0 < mv0) { mv0 = cur0; w0 = j0; }
            if (!(um & 2) && cur1 < mv1) { mv1 = cur1; w1 = j0; }
            if (!(um & 4) && cur2 < mv2) { mv2 = cur2; w2 = j0; }

            // lane-local argmin (slot order = ascending j, strict < keeps first)
            double bestv = INF; int bestj = 0x7FFFFFFF; int bestp = 0;
            if (!(um & 1))                { bestv = mv0; bestj = ja; bestp = pa; }
            if (!(um & 2) && mv1 < bestv) { bestv = mv1; bestj = jb; bestp = pb; }
            if (!(um & 4) && mv2 < bestv) { bestv = mv2; bestj = jc; bestp = pc; }

            // orderable f32 key (monotone under f64->f32 RN; -0 canonicalized)
            float kf = (float)bestv + 0.0f;
            unsigned key = ord32(kf);
            unsigned x = key;
            DPPMIN(x, 0x111);   // row_shr:1
            DPPMIN(x, 0x112);   // row_shr:2
            DPPMIN(x, 0x114);   // row_shr:4
            DPPMIN(x, 0x118);   // row_shr:8
            DPPMIN(x, 0x142);   // row_bcast:15
            DPPMIN(x, 0x143);   // row_bcast:31
            unsigned kmin = (unsigned)__builtin_amdgcn_readlane((int)x, 63);

            unsigned long long cm = __ballot(key == kmin);
            int j1, pj; double delta;
            if (__popcll(cm) == 1) {
                int L = (int)__builtin_ctzll(cm);
                j1 = __builtin_amdgcn_readlane(bestj, L);
                pj = __builtin_amdgcn_readlane(bestp, L);
                int hi = __builtin_amdgcn_readlane(__double2hiint(bestv), L);
                int lo = __builtin_amdgcn_readlane(__double2loint(bestv), L);
                delta = __hiloint2double(hi, lo);
            } else {
                // rare: exact f64 resolve with first-index (smallest j) tie-break
                double bv = INF; int bj = 0x7FFFFFFF; int bp = 0;
                unsigned long long m = cm;
                while (m) {
                    int L = (int)__builtin_ctzll(m); m &= m - 1;
                    int hi = __builtin_amdgcn_readlane(__double2hiint(bestv), L);
                    int lo = __builtin_amdgcn_readlane(__double2loint(bestv), L);
                    double dv = __hiloint2double(hi, lo);
                    int dj = __builtin_amdgcn_readlane(bestj, L);
                    int dp = __builtin_amdgcn_readlane(bestp, L);
                    if (dv < bv || (dv == bv && dj < bj)) { bv = dv; bj = dj; bp = dp; }
                }
                j1 = bj; pj = bp; delta = bv;
            }

            // issue next-iteration loads early (addresses disjoint from updates:
            // pj = p[j1], j1 free => pj not among rows of used cols, pj != i)
            int pr = (pj > 0) ? pj : 1;
            double ui_n = u[pr];
            int bn = (pr - 1) * T_ - 1;
            float c0n = cl[bn + ja];
            float c1n = cl[bn + jb];
            float c2n = cl[bn + jcs];

            // dual / minv updates (overlap the loads above)
            if (um & 1) { v0 -= delta; u[pa] += delta; } else { mv0 -= delta; }
            if (um & 2) { v1 -= delta; u[pb] += delta; } else { mv1 -= delta; }
            if (va2) {
                if (um & 4) { v2 -= delta; u[pc] += delta; } else { mv2 -= delta; }
            }
            if (lane == 0) u[i] += delta;     // col 0: p[0] = i

            j0 = j1;
            if (pj == 0) break;
            ui0 = ui_n; c0 = c0n; c1 = c1n; c2 = c2n;
        }

        // augment: walk way chain wave-uniformly via shuffles
        int jj = j0;
        while (jj != 0) {
            int sj = (jj - 1) >> 6, lj = (jj - 1) & 63;
            int jn = __shfl(sel3i(sj, w0, w1, w2), lj);
            int rown;
            if (jn == 0) rown = i;
            else {
                int sn = (jn - 1) >> 6, ln = (jn - 1) & 63;
                rown = __shfl(sel3i(sn, pa, pb, pc), ln);
            }
            if (lane == lj) {
                if (sj == 0) pa = rown; else if (sj == 1) pb = rown; else pc = rown;
            }
            jj = jn;
        }
    }

    // extract: col j matched to row p[j]-1; perfect matching covers all rows
    assign[b * P_ + (pa - 1)] = ja - 1;
    assign[b * P_ + (pb - 1)] = jb - 1;
    if (va2) assign[b * P_ + (pc - 1)] = jc - 1;
}

// ---------------------------------------------------------------------------
// Kernel 3: per-i partial loss: mean over (b,k) of cost[b, k, assign_i[k]]
// ---------------------------------------------------------------------------
__global__ void gather_kernel(const float* __restrict__ cost,
                              const int* __restrict__ assign,
                              double* __restrict__ partial) {
    const int i = blockIdx.x;
    const int* a = assign + i * P_;
    double s = 0.0;
    for (int idx = threadIdx.x; idx < B_ * P_; idx += blockDim.x) {
        int b = idx / P_;
        int k = idx % P_;
        s += (double)cost[((size_t)b * P_ + k) * T_ + a[k]];
    }
    __shared__ double red[256];
    red[threadIdx.x] = s;
    __syncthreads();
    for (int off = 128; off >= 1; off >>= 1) {
        if (threadIdx.x < off) red[threadIdx.x] += red[threadIdx.x + off];
        __syncthreads();
    }
    if (threadIdx.x == 0) partial[i] = red[0] / (double)(B_ * P_);
}

// ---------------------------------------------------------------------------
// Kernel 4: final sum (deterministic order) -> f32 scalar
// ---------------------------------------------------------------------------
__global__ void finalize_kernel(const double* __restrict__ partial,
                                float* __restrict__ out) {
    if (threadIdx.x == 0 && blockIdx.x == 0) {
        double s = 0.0;
        for (int i = 0; i < B_; ++i) s += partial[i];
        out[0] = (float)s;
    }
}

// ---------------------------------------------------------------------------
extern "C" void kernel_launch(void* const* d_in, const int* in_sizes, int n_in,
                              void* d_out, int out_size, void* d_ws, size_t ws_size,
                              hipStream_t stream) {
    const float* prob   = (const float*)d_in[0];   // [64,150,81]
    const float* pbox   = (const float*)d_in[1];   // [64,150,4]
    const float* labels = (const float*)d_in[2];   // [64,150,5]
    float* out = (float*)d_out;

    char* ws = (char*)d_ws;
    float*  cost    = (float*) ws;                               // 5,760,000 B
    int*    assign  = (int*)   (ws + (size_t)B_ * P_ * T_ * 4);  // 38,400 B
    double* partial = (double*)(ws + (size_t)B_ * P_ * T_ * 4 + (size_t)B_ * P_ * 4);

    const int total = B_ * P_ * T_;
    cost_kernel<<<(total + 255) / 256, 256, 0, stream>>>(prob, pbox, labels, cost);

    hungarian_kernel<<<B_, 64, SM_TOTAL, stream>>>(cost, assign);

    gather_kernel<<<B_, 256, 0, stream>>>(cost, assign, partial);

    finalize_kernel<<<1, 64, 0, stream>>>(partial, out);
}

// Round 4
// 1239.587 us; speedup vs baseline: 3.3931x; 1.7396x over previous
//
#include <hip/hip_runtime.h>
#include <hip/hip_bf16.h>
#include <math.h>

// Problem constants (match reference)
#define B_   64
#define P_   150   // n_pred (rows)
#define T_   150   // n_true (cols)
#define C_   81
#define NOOBJ 80

// ---------------------------------------------------------------------------
// Kernel 1: cost matrix [B, P, T] in f32
// ---------------------------------------------------------------------------
__global__ void cost_kernel(const float* __restrict__ prob,
                            const float* __restrict__ pbox,
                            const float* __restrict__ labels,
                            float* __restrict__ cost) {
    int idx = blockIdx.x * blockDim.x + threadIdx.x;
    const int total = B_ * P_ * T_;
    if (idx >= total) return;
    int t  = idx % T_;
    int p  = (idx / T_) % P_;
    int b  = idx / (P_ * T_);

    const float* lb5 = labels + ((size_t)b * T_ + t) * 5;
    const float inv = 1.0f / 320.0f;
    float lcx = lb5[0] * inv, lcy = lb5[1] * inv, lw = lb5[2] * inv, lh = lb5[3] * inv;
    int cls = (int)lb5[4];

    const float* pb = pbox + ((size_t)b * P_ + p) * 4;
    float pcx = pb[0], pcy = pb[1], pw = pb[2], ph = pb[3];

    float nll = -logf(prob[((size_t)b * P_ + p) * C_ + cls]);

    float l1 = 0.25f * (fabsf(pcx - lcx) + fabsf(pcy - lcy) +
                        fabsf(pw - lw)   + fabsf(ph - lh));

    float px0 = pcx - 0.5f * pw, py0 = pcy - 0.5f * ph;
    float px1 = pcx + 0.5f * pw, py1 = pcy + 0.5f * ph;
    float lx0 = lcx - 0.5f * lw, ly0 = lcy - 0.5f * lh;
    float lx1 = lcx + 0.5f * lw, ly1 = lcy + 0.5f * lh;

    float ltx = fmaxf(px0, lx0), lty = fmaxf(py0, ly0);
    float rbx = fminf(px1, lx1), rby = fminf(py1, ly1);
    float iw = fmaxf(rbx - ltx, 0.f), ih = fmaxf(rby - lty, 0.f);
    float inter = iw * ih;
    float ap = (px1 - px0) * (py1 - py0);
    float al = (lx1 - lx0) * (ly1 - ly0);
    float un = ap + al - inter;
    float iou = inter / (un + 1e-7f);

    float cx0 = fminf(px0, lx0), cy0 = fminf(py0, ly0);
    float cx1 = fmaxf(px1, lx1), cy1 = fmaxf(py1, ly1);
    float cw = fmaxf(cx1 - cx0, 0.f), ch = fmaxf(cy1 - cy0, 0.f);
    float enc = cw * ch;
    float giou = iou - (enc - un) / (enc + 1e-7f);
    float gl = 1.0f - giou;

    float mask = (cls != NOOBJ) ? 1.0f : 0.0f;
    cost[idx] = nll + (5.0f * l1 + 2.0f * gl) * mask;
}

// ---------------------------------------------------------------------------
// Kernel 2: Hungarian (JV), one wave per batch, register-resident state.
//  - v/minv/way/p per-lane registers (3 column slots per lane)
//  - u of tree rows accumulated in REGISTERS during a phase (bit-exact same
//    add sequence as numpy), written back to LDS once per phase
//  - column-reduction dual init v[j] = min_i c[i][j] (exact; LSAP optimum is
//    unique for continuous random data -> same assignment as reference)
//  - argmin via DPP min on orderable f32 key + exact f64 tie resolve
// ---------------------------------------------------------------------------
#define SM_U      (P_ * T_ * 4)           // after 90000 B cost tile (8B aligned)
#define SM_TOTAL  (SM_U + 152 * 8)

__device__ __forceinline__ unsigned ord32(float f) {
    unsigned bits = __float_as_uint(f);
    return (bits & 0x80000000u) ? ~bits : (bits | 0x80000000u);
}

#define DPPMIN(x, ctrl)                                                          \
    do {                                                                         \
        unsigned _t = (unsigned)__builtin_amdgcn_update_dpp(                     \
            (int)(x), (int)(x), (ctrl), 0xF, 0xF, false);                        \
        (x) = (_t < (x)) ? _t : (x);                                             \
    } while (0)

__device__ __forceinline__ int sel3i(int s, int a, int b, int c) {
    return s == 0 ? a : (s == 1 ? b : c);
}

__global__ __launch_bounds__(64) void hungarian_kernel(const float* __restrict__ cost,
                                                       int* __restrict__ assign) {
    const int b = blockIdx.x;
    const int lane = threadIdx.x;
    const float* Cg = cost + (size_t)b * (P_ * T_);

    extern __shared__ char smem[];
    float*  cl = (float*)smem;             // [150*150] f32 cost tile
    double* u  = (double*)(smem + SM_U);   // [151] f64 row duals

    for (int i4 = lane; i4 < (P_ * T_) / 4; i4 += 64)
        ((float4*)cl)[i4] = ((const float4*)Cg)[i4];
    for (int r = lane; r <= P_; r += 64) u[r] = 0.0;
    __syncthreads();

    // per-lane column slots
    const int ja = 1 + lane;            // slot 0: cols 1..64
    const int jb = 65 + lane;           // slot 1: cols 65..128
    const int jc = 129 + lane;          // slot 2: cols 129..150 (lanes 0..21)
    const bool va2 = (jc <= T_);
    const int jcs = va2 ? jc : T_;      // safe address for slot-2 loads

    // column-reduction dual init: v[j] = min_i c[i][j] (exact f32 min)
    float m0 = cl[ja - 1], m1 = cl[jb - 1], m2 = cl[jcs - 1];
    #pragma unroll 4
    for (int r = 1; r < P_; ++r) {
        int rb_ = r * T_;
        m0 = fminf(m0, cl[rb_ + ja - 1]);
        m1 = fminf(m1, cl[rb_ + jb - 1]);
        m2 = fminf(m2, cl[rb_ + jcs - 1]);
    }
    double v0 = (double)m0, v1 = (double)m1, v2 = va2 ? (double)m2 : 0.0;
    int pa = 0, pb = 0, pc = 0;             // p[j]: row matched to col (0=none)

    const double INF = __builtin_inf();

    for (int i = 1; i <= P_; ++i) {
        double mv0 = INF, mv1 = INF, mv2 = INF;
        int w0 = 0, w1 = 0, w2 = 0;
        int um = va2 ? 0 : 4;           // invalid slot2 marked used
        double ua = 0.0, ub = 0.0, uc = 0.0;   // register u of tree rows
        int ra = 0, rb = 0, rc = 0;            // which row each used slot tracks
        int j0 = 0;
        int i0cur = i;                  // row entering the tree this iteration

        // prefetch iteration 0: i0 = i
        double ui0 = u[i];
        double u_i = ui0;               // register copy of u[i] (col-0 row)
        int base = (i - 1) * T_ - 1;
        float c0 = cl[base + ja];
        float c1 = cl[base + jb];
        float c2 = cl[base + jcs];

        while (true) {
            // mark used[j0]; record its row + phase-start u (== prefetched ui0)
            if (j0 > 0 && lane == ((j0 - 1) & 63)) {
                int sl = (j0 - 1) >> 6;
                if (sl == 0)      { um |= 1; ua = ui0; ra = i0cur; }
                else if (sl == 1) { um |= 2; ub = ui0; rb = i0cur; }
                else              { um |= 4; uc = ui0; rc = i0cur; }
            }

            // scan free columns (numpy order: (c - u) - v)
            double cur0 = ((double)c0 - ui0) - v0;
            double cur1 = ((double)c1 - ui0) - v1;
            double cur2 = ((double)c2 - ui0) - v2;
            if (!(um & 1) && cur0 < mv0) { mv0 = cur0; w0 = j0; }
            if (!(um & 2) && cur1 < mv1) { mv1 = cur1; w1 = j0; }
            if (!(um & 4) && cur2 < mv2) { mv2 = cur2; w2 = j0; }

            // lane-local argmin (slot order = ascending j, strict < keeps first)
            double bestv = INF; int bestj = 0x7FFFFFFF; int bestp = 0;
            if (!(um & 1))                { bestv = mv0; bestj = ja; bestp = pa; }
            if (!(um & 2) && mv1 < bestv) { bestv = mv1; bestj = jb; bestp = pb; }
            if (!(um & 4) && mv2 < bestv) { bestv = mv2; bestj = jc; bestp = pc; }

            // orderable f32 key (monotone under f64->f32 RN; -0 canonicalized)
            float kf = (float)bestv + 0.0f;
            unsigned key = ord32(kf);
            unsigned x = key;
            DPPMIN(x, 0x111);   // row_shr:1
            DPPMIN(x, 0x112);   // row_shr:2
            DPPMIN(x, 0x114);   // row_shr:4
            DPPMIN(x, 0x118);   // row_shr:8
            DPPMIN(x, 0x142);   // row_bcast:15
            DPPMIN(x, 0x143);   // row_bcast:31
            unsigned kmin = (unsigned)__builtin_amdgcn_readlane((int)x, 63);

            unsigned long long cm = __ballot(key == kmin);
            int j1, pj; double delta;
            int pk = (bestp << 8) | (bestj & 0xFF);
            if (__popcll(cm) == 1) {
                int L = (int)__builtin_ctzll(cm);
                int pkw = __builtin_amdgcn_readlane(pk, L);
                j1 = pkw & 0xFF;
                pj = pkw >> 8;
                int hi = __builtin_amdgcn_readlane(__double2hiint(bestv), L);
                int lo = __builtin_amdgcn_readlane(__double2loint(bestv), L);
                delta = __hiloint2double(hi, lo);
            } else {
                // rare: exact f64 resolve with first-index (smallest j) tie-break
                double bv = INF; int bj = 0x7FFFFFFF; int bp = 0;
                unsigned long long m = cm;
                while (m) {
                    int L = (int)__builtin_ctzll(m); m &= m - 1;
                    int hi = __builtin_amdgcn_readlane(__double2hiint(bestv), L);
                    int lo = __builtin_amdgcn_readlane(__double2loint(bestv), L);
                    double dv = __hiloint2double(hi, lo);
                    int dj = __builtin_amdgcn_readlane(bestj, L);
                    int dp = __builtin_amdgcn_readlane(bestp, L);
                    if (dv < bv || (dv == bv && dj < bj)) { bv = dv; bj = dj; bp = dp; }
                }
                j1 = bj; pj = bp; delta = bv;
            }

            // issue next-iteration loads early (pj's row is outside the tree,
            // so its LDS u value is current; addresses disjoint from writes)
            int pr = (pj > 0) ? pj : 1;
            double ui_n = u[pr];
            int bn = (pr - 1) * T_ - 1;
            float c0n = cl[bn + ja];
            float c1n = cl[bn + jb];
            float c2n = cl[bn + jcs];

            // register-only dual / minv updates (same add order as reference)
            if (um & 1) { v0 -= delta; ua += delta; } else { mv0 -= delta; }
            if (um & 2) { v1 -= delta; ub += delta; } else { mv1 -= delta; }
            if (va2) {
                if (um & 4) { v2 -= delta; uc += delta; } else { mv2 -= delta; }
            }
            u_i += delta;                 // col 0 (row i), uniform across lanes

            i0cur = pj;
            j0 = j1;
            if (pj == 0) break;
            ui0 = ui_n; c0 = c0n; c1 = c1n; c2 = c2n;
        }

        // phase end: write tree rows' duals back to LDS (rows are distinct)
        if (um & 1) u[ra] = ua;
        if (um & 2) u[rb] = ub;
        if (va2 && (um & 4)) u[rc] = uc;
        if (lane == 0) u[i] = u_i;

        // augment: walk way chain wave-uniformly via shuffles
        int jj = j0;
        while (jj != 0) {
            int sj = (jj - 1) >> 6, lj = (jj - 1) & 63;
            int jn = __shfl(sel3i(sj, w0, w1, w2), lj);
            int rown;
            if (jn == 0) rown = i;
            else {
                int sn = (jn - 1) >> 6, ln = (jn - 1) & 63;
                rown = __shfl(sel3i(sn, pa, pb, pc), ln);
            }
            if (lane == lj) {
                if (sj == 0) pa = rown; else if (sj == 1) pb = rown; else pc = rown;
            }
            jj = jn;
        }
    }

    // extract: col j matched to row p[j]-1; perfect matching covers all rows
    assign[b * P_ + (pa - 1)] = ja - 1;
    assign[b * P_ + (pb - 1)] = jb - 1;
    if (va2) assign[b * P_ + (pc - 1)] = jc - 1;
}

// ---------------------------------------------------------------------------
// Kernel 3: per-i partial loss: mean over (b,k) of cost[b, k, assign_i[k]]
// ---------------------------------------------------------------------------
__global__ void gather_kernel(const float* __restrict__ cost,
                              const int* __restrict__ assign,
                              double* __restrict__ partial) {
    const int i = blockIdx.x;
    const int* a = assign + i * P_;
    double s = 0.0;
    for (int idx = threadIdx.x; idx < B_ * P_; idx += blockDim.x) {
        int b = idx / P_;
        int k = idx % P_;
        s += (double)cost[((size_t)b * P_ + k) * T_ + a[k]];
    }
    __shared__ double red[256];
    red[threadIdx.x] = s;
    __syncthreads();
    for (int off = 128; off >= 1; off >>= 1) {
        if (threadIdx.x < off) red[threadIdx.x] += red[threadIdx.x + off];
        __syncthreads();
    }
    if (threadIdx.x == 0) partial[i] = red[0] / (double)(B_ * P_);
}

// ---------------------------------------------------------------------------
// Kernel 4: final sum (deterministic order) -> f32 scalar
// ---------------------------------------------------------------------------
__global__ void finalize_kernel(const double* __restrict__ partial,
                                float* __restrict__ out) {
    if (threadIdx.x == 0 && blockIdx.x == 0) {
        double s = 0.0;
        for (int i = 0; i < B_; ++i) s += partial[i];
        out[0] = (float)s;
    }
}

// ---------------------------------------------------------------------------
extern "C" void kernel_launch(void* const* d_in, const int* in_sizes, int n_in,
                              void* d_out, int out_size, void* d_ws, size_t ws_size,
                              hipStream_t stream) {
    const float* prob   = (const float*)d_in[0];   // [64,150,81]
    const float* pbox   = (const float*)d_in[1];   // [64,150,4]
    const float* labels = (const float*)d_in[2];   // [64,150,5]
    float* out = (float*)d_out;

    char* ws = (char*)d_ws;
    float*  cost    = (float*) ws;                               // 5,760,000 B
    int*    assign  = (int*)   (ws + (size_t)B_ * P_ * T_ * 4);  // 38,400 B
    double* partial = (double*)(ws + (size_t)B_ * P_ * T_ * 4 + (size_t)B_ * P_ * 4);

    const int total = B_ * P_ * T_;
    cost_kernel<<<(total + 255) / 256, 256, 0, stream>>>(prob, pbox, labels, cost);

    hungarian_kernel<<<B_, 64, SM_TOTAL, stream>>>(cost, assign);

    gather_kernel<<<B_, 256, 0, stream>>>(cost, assign, partial);

    finalize_kernel<<<1, 64, 0, stream>>>(partial, out);
}